// Round 1
// baseline (589.323 us; speedup 1.0000x reference)
//
#include <hip/hip_runtime.h>
#include <stdint.h>

typedef unsigned short u16;
typedef float f32x4 __attribute__((ext_vector_type(4)));
typedef short bf16x8 __attribute__((ext_vector_type(8)));

#define MFMA(a,b,c) __builtin_amdgcn_mfma_f32_16x16x32_bf16((a),(b),(c),0,0,0)

__device__ __forceinline__ u16 f2b(float f){
  union { float f; unsigned u; } x; x.f = f;
  unsigned r = x.u + 0x7FFFu + ((x.u >> 16) & 1u);   // RNE
  return (u16)(r >> 16);
}
__device__ __forceinline__ float b2f(u16 b){
  union { unsigned u; float f; } x; x.u = ((unsigned)b) << 16;
  return x.f;
}
// runtime-dtype input load (flag: 1=bf16 inputs, 0=fp32 inputs)
__device__ __forceinline__ float ldin(const void* p, long long i, int isbf){
  return isbf ? b2f(((const u16*)p)[i]) : ((const float*)p)[i];
}
typedef const __attribute__((address_space(1))) void gas_t;
typedef __attribute__((address_space(3))) void sas_t;
__device__ __forceinline__ void gl16(const void* g, void* l){
  __builtin_amdgcn_global_load_lds((gas_t*)g, (sas_t*)l, 16, 0, 0);
}
__device__ __forceinline__ float sigm(float x){ return 1.f/(1.f + __expf(-x)); }
__device__ __forceinline__ float tanh_f(float x){
  float e2 = __expf(-2.f*fabsf(x));
  float t = (1.f - e2)/(1.f + e2);
  return copysignf(t, x);
}

// N=4 I=64 C=256 G=8 Cg=32 K=9 H=W=48 HW=2304 Hd=Wd=40 D=1600 pad=4 (56x56 padded)
// workspace map (~96 MB)
static constexpr size_t OFF_FLAG = 0;
static constexpr size_t OFF_WB = 256;                     // conv w bf16 [g][81][224][64], ci-chunks xor oc&7
static constexpr size_t SZ_WB  = (size_t)8*81*224*64*2;
static constexpr size_t OFF_WP = OFF_WB + SZ_WB;          // proj w bf16 [256][320], chunk xor oc&7
static constexpr size_t SZ_WP  = (size_t)256*320*2;
static constexpr size_t OFF_UT = OFF_WP + SZ_WP;          // [n][2304][320] bf16 (inp;h transposed)
static constexpr size_t SZ_UT  = (size_t)4*2304*320*2;
static constexpr size_t OFF_XH = OFF_UT + SZ_UT;          // [n][g][56][56][64] bf16, zero pad
static constexpr size_t SZ_XH  = (size_t)32*3136*64*2;
static constexpr size_t OFF_QB = OFF_XH + SZ_XH;          // [n][g][32][2304] bf16
static constexpr size_t SZ_QB  = (size_t)32*32*2304*2;
static constexpr size_t OFF_KB = OFF_QB + SZ_QB;          // [n][g][32][1600] bf16
static constexpr size_t SZ_KB  = (size_t)32*32*1600*2;
static constexpr size_t OFF_VB = OFF_KB + SZ_KB;          // [n][g][32][1600] bf16
static constexpr size_t OFF_GP = OFF_VB + SZ_KB;          // [n][g][4][32][2304] f32 gate pre-acts
static constexpr size_t SZ_GP  = (size_t)32*4*32*2304*4;
static constexpr size_t OFF_AB = OFF_GP + SZ_GP;          // [n][g][32][2304] f32 attention out
static constexpr size_t SZ_AB  = (size_t)32*32*2304*4;

// ---------------- probe: detect bf16 vs fp32 inputs ----------------
__global__ void k_probe(const unsigned* u, int* flag){
  int t = threadIdx.x;
  unsigned v = u[t];
  unsigned e = (v >> 7) & 0xFF;     // exponent field of low-16 as bf16
  int is = (e >= 0x70 && e <= 0x88) ? 1 : 0;
  unsigned long long m = __ballot(is);
  __shared__ int cnt[4];
  if ((t & 63) == 0) cnt[t >> 6] = __popcll(m);
  __syncthreads();
  if (t == 0) *flag = (cnt[0]+cnt[1]+cnt[2]+cnt[3] >= 128) ? 1 : 0;
}

// ---------------- pack conv weights ----------------
// grid 1792 = g(8) x conv(7) x ocl(32); WB[g][kk][oc=conv*32+ocl][swz(ci)]
__global__ void k_packw(const void* Wq, const void* Wk, const void* Wv,
                        const void* Wi, const void* Wf, const void* Wg,
                        const void* Wo, u16* WB, const int* flag){
  int b = blockIdx.x; int ocl = b & 31; int tt = (b >> 5) % 7; int g = b / 224;
  int tid = threadIdx.x; int isbf = *flag;
  const void* srcs[7] = {Wq, Wk, Wv, Wi, Wf, Wg, Wo};
  const void* src = srcs[tt];
  __shared__ float s[5184];
  long long base = (long long)(g*32 + ocl) * 5184;   // [oc][ci=64][9][9]
  for (int i = tid; i < 5184; i += 256) s[i] = ldin(src, base + i, isbf);
  __syncthreads();
  int oc = tt*32 + ocl;
  for (int i = tid; i < 5184; i += 256){
    int kk = i >> 6, ci = i & 63;
    int pos = ((((ci >> 3) ^ (ocl & 7)) << 3) | (ci & 7));
    WB[((size_t)(g*81 + kk)*224 + oc)*64 + pos] = f2b(s[ci*81 + kk]);
  }
}

// ---------------- pack proj weights [256][320] = [Wx|Wxg], chunk-swizzled ----------------
__global__ void k_packp(const void* Wx, const void* Wxg, u16* Wp, const int* flag){
  int el = blockIdx.x*256 + threadIdx.x;   // 81920
  int isbf = *flag;
  if (el >= 81920) return;
  int oc = el / 320, k = el % 320;
  float v = (k < 64) ? ldin(Wx, (long long)oc*64 + k, isbf)
                     : ldin(Wxg, (long long)oc*256 + (k - 64), isbf);
  int win = k >> 6, pos = k & 63;
  int dpos = (win << 6) | ((((pos >> 3) ^ (oc & 7)) << 3)) | (pos & 7);
  Wp[(size_t)oc*320 + dpos] = f2b(v);
}

// ---------------- build U_T [n][q][320] + fill h-part of xh_pad ----------------
// grid 360 = n(4) x s(5: inp, h0..h3) x qb(18)
__global__ void k_ut(const void* inp, const void* h, u16* UT, u16* xh, const int* flag){
  int b = blockIdx.x; int qb = b % 18; int s = (b / 18) % 5; int n = b / 90;
  int tid = threadIdx.x; int isbf = *flag;
  __shared__ float sb[64][129];
  const void* src = (s == 0) ? inp : h;
  long long base = (s == 0) ? (long long)n*64*2304 : ((long long)n*256 + (s-1)*64)*2304;
  for (int i = 0; i < 32; i++){
    int el = tid + i*256; int r = el >> 7, q = el & 127;
    sb[r][q] = ldin(src, base + (long long)r*2304 + qb*128 + q, isbf);
  }
  __syncthreads();
  int koff = (s == 0) ? 0 : 64 + (s-1)*64;
  for (int i = 0; i < 4; i++){
    int chunk = tid + i*256;                 // 1024 chunks of 8
    int q = chunk >> 3, c8 = chunk & 7;
    bf16x8 v;
    #pragma unroll
    for (int j = 0; j < 8; j++) v[j] = (short)f2b(sb[c8*8 + j][q]);
    *(bf16x8*)&UT[((size_t)(n*2304 + qb*128 + q))*320 + koff + c8*8] = v;
  }
  if (s > 0){
    for (int i = 0; i < 4; i++){
      int chunk = tid + i*256;               // q(128) x gg(2) x seg(4)
      int q = chunk >> 3, gg = (chunk >> 2) & 1, seg = chunk & 3;
      int g = (s-1)*2 + gg;
      int qg = qb*128 + q; int y = qg / 48, x = qg - y*48;
      bf16x8 v;
      #pragma unroll
      for (int j = 0; j < 8; j++) v[j] = (short)f2b(sb[gg*32 + seg*8 + j][q]);
      *(bf16x8*)&xh[(((size_t)((n*8+g)*56 + y+4))*56 + (x+4))*64 + 32 + seg*8] = v;
    }
  }
}

// ---------------- proj GEMM: x = [Wx|Wxg]·[inp;h] -> xh_pad ci[0:32) ----------------
// D[q][oc]; A=U_T tile [144][64], B=Wp tile [256][64]; grid 64 = n*16, 384 thr (6 waves: wm q x wn oc)
__global__ __launch_bounds__(384) void k_proj(const u16* Wp, const u16* UT, u16* xh){
  int b = blockIdx.x; int qblk = b & 15; int n = b >> 4;
  int tid = threadIdx.x; int lane = tid & 63; int wid = tid >> 6;
  int wm = wid % 3, wn = wid / 3;
  int quad = lane >> 4, m16 = lane & 15;
  __shared__ __align__(16) u16 lA[144*64];
  __shared__ __align__(16) u16 lB[256*64];
  size_t abase[3];
  #pragma unroll
  for (int r = 0; r < 3; r++){
    int chunk = tid + r*384; int j = chunk >> 3, cs = chunk & 7;
    int cc = cs ^ (j & 7);
    abase[r] = ((size_t)(n*2304 + qblk*144 + j))*320 + cc*8;
  }
  f32x4 acc[3][8];
  #pragma unroll
  for (int a = 0; a < 3; a++)
    #pragma unroll
    for (int c = 0; c < 8; c++) acc[a][c] = (f32x4){0.f,0.f,0.f,0.f};

  for (int kb = 0; kb < 5; kb++){
    __syncthreads();
    #pragma unroll
    for (int r = 0; r < 3; r++)
      gl16(&UT[abase[r] + kb*64], &lA[(tid + r*384)*8]);
    #pragma unroll
    for (int r = 0; r < 6; r++){
      int chunk = tid + r*384;
      if (chunk < 2048)
        gl16(&Wp[(size_t)(chunk >> 3)*320 + kb*64 + (chunk & 7)*8], &lB[chunk*8]);
    }
    __syncthreads();
    #pragma unroll
    for (int ks = 0; ks < 2; ks++){
      int sw = ((ks*4 + quad) ^ (lane & 7))*8;
      bf16x8 af[3], bfr[8];
      #pragma unroll
      for (int mt = 0; mt < 3; mt++)
        af[mt] = *(const bf16x8*)&lA[(wm*48 + mt*16 + m16)*64 + sw];
      #pragma unroll
      for (int nt = 0; nt < 8; nt++)
        bfr[nt] = *(const bf16x8*)&lB[(wn*128 + nt*16 + m16)*64 + sw];
      #pragma unroll
      for (int mt = 0; mt < 3; mt++)
        #pragma unroll
        for (int nt = 0; nt < 8; nt++)
          acc[mt][nt] = MFMA(af[mt], bfr[nt], acc[mt][nt]);
    }
  }
  // epilogue: row=q, col=oc
  #pragma unroll
  for (int mt = 0; mt < 3; mt++)
    #pragma unroll
    for (int nt = 0; nt < 8; nt++)
      #pragma unroll
      for (int r = 0; r < 4; r++){
        int q = qblk*144 + wm*48 + mt*16 + quad*4 + r;
        int oc = wn*128 + nt*16 + m16;
        int y = q / 48, x = q - y*48;
        int g = oc >> 5, ci = oc & 31;
        xh[(((size_t)((n*8+g)*56 + y+4))*56 + (x+4))*64 + ci] = f2b(acc[mt][nt][r]);
      }
}

// ---------------- fused 7-conv implicit GEMM ----------------
// per (n,g): OUT[224][2304]; WG = 3 rows x 48 = 144 spatial, all 224 oc.
// grid 512 = n(4) x g(8) x qblk(16); 384 thr = 6 waves (wm: 2x112 oc, wn: 3x48 spatial)
__global__ __launch_bounds__(384) void k_conv(const u16* WB, const u16* xh,
                                              u16* Qb, u16* Kb, u16* Vb, float* Gp){
  int b = blockIdx.x; int qblk = b & 15; int gg = (b >> 4) & 7; int n = b >> 7;
  int tid = threadIdx.x; int lane = tid & 63; int wid = tid >> 6;
  int wm = wid & 1, wn = wid >> 1;
  int quad = lane >> 4, m16 = lane & 15;
  int y0 = qblk*3;
  __shared__ __align__(16) u16 lA[224*64];
  __shared__ __align__(16) u16 lB[144*64];
  size_t bbase[3];
  #pragma unroll
  for (int r = 0; r < 3; r++){
    int chunk = tid + r*384; int j = chunk >> 3, cs = chunk & 7;
    int cc = cs ^ (j & 7);
    int dy = j / 48, xx = j - dy*48;
    bbase[r] = ((size_t)((n*8+gg)*3136) + (y0+dy)*56 + xx)*64 + cc*8;
  }
  const u16* WBg = WB + (size_t)gg*81*14336;
  f32x4 acc[7][3];
  #pragma unroll
  for (int a = 0; a < 7; a++)
    #pragma unroll
    for (int c = 0; c < 3; c++) acc[a][c] = (f32x4){0.f,0.f,0.f,0.f};

  for (int kk = 0; kk < 81; kk++){
    int ky = kk / 9, kx = kk - ky*9;
    __syncthreads();
    #pragma unroll
    for (int r = 0; r < 5; r++){
      int chunk = tid + r*384;
      if (chunk < 1792)
        gl16(&WBg[(size_t)kk*14336 + chunk*8], &lA[chunk*8]);
    }
    size_t koff = (size_t)(ky*56 + kx)*64;
    #pragma unroll
    for (int r = 0; r < 3; r++)
      gl16(&xh[bbase[r] + koff], &lB[(tid + r*384)*8]);
    __syncthreads();
    #pragma unroll
    for (int ks = 0; ks < 2; ks++){
      int sw = ((ks*4 + quad) ^ (lane & 7))*8;
      bf16x8 af[7], bfr[3];
      #pragma unroll
      for (int mt = 0; mt < 7; mt++)
        af[mt] = *(const bf16x8*)&lA[(wm*112 + mt*16 + m16)*64 + sw];
      #pragma unroll
      for (int nt = 0; nt < 3; nt++)
        bfr[nt] = *(const bf16x8*)&lB[(wn*48 + nt*16 + m16)*64 + sw];
      #pragma unroll
      for (int mt = 0; mt < 7; mt++)
        #pragma unroll
        for (int nt = 0; nt < 3; nt++)
          acc[mt][nt] = MFMA(af[mt], bfr[nt], acc[mt][nt]);
    }
  }
  // epilogue: row = oc, col = spatial
  int y = y0 + wn;
  size_t ng = (size_t)(n*8 + gg);
  #pragma unroll
  for (int mt = 0; mt < 7; mt++){
    int ocb = wm*112 + mt*16 + quad*4;
    #pragma unroll
    for (int nt = 0; nt < 3; nt++){
      int x = nt*16 + m16;
      int q = y*48 + x;
      #pragma unroll
      for (int r = 0; r < 4; r++){
        float v = acc[mt][nt][r];
        int oc = ocb + r;
        int t7 = oc >> 5, ocl = oc & 31;
        if (t7 == 0){
          Qb[(ng*32 + ocl)*2304 + q] = f2b(v);
        } else if (t7 <= 2){
          if ((unsigned)(y-4) < 40u && (unsigned)(x-4) < 40u){
            int d = (y-4)*40 + (x-4);
            (t7 == 1 ? Kb : Vb)[(ng*32 + ocl)*1600 + d] = f2b(v);
          }
        } else {
          Gp[((ng*4 + (t7-3))*32 + ocl)*2304 + q] = v;
        }
      }
    }
  }
}

// ---------------- attention: S=tau Q^T K, softmax over d, O^T = V P^T ----------------
// grid 576 = n(4) x g(8) x qb(18); 256 thr = 4 waves, 32 q each; d-loop 25 x 64
__global__ __launch_bounds__(256) void k_attn(const u16* Qb, const u16* Kb, const u16* Vb,
                                              float* Ab, const void* tau, const int* flag){
  int b = blockIdx.x; int qb = b % 18; int g = (b / 18) & 7; int n = b / 144;
  int tid = threadIdx.x; int lane = tid & 63; int wid = tid >> 6;
  int quad = lane >> 4, m16 = lane & 15;
  int isbf = *flag;
  __shared__ __align__(16) u16 sQ[128*40];     // [q][c] stride 40
  __shared__ __align__(16) u16 sK[64*40];      // [d][c] stride 40
  __shared__ __align__(16) u16 sV[32*72];      // [c][d] stride 72
  __shared__ __align__(16) u16 sP[4][32*72];   // per-wave [q][d] stride 72
  __shared__ float sL[128];
  size_t ng = (size_t)(n*8 + g);
  const u16* Qg = Qb + ng*32*2304;
  const u16* Kg = Kb + ng*32*1600;
  const u16* Vg = Vb + ng*32*1600;
  float tauv = ldin(tau, g, isbf);
  // Q tile transpose into LDS
  for (int i = 0; i < 16; i++){
    int el = tid + i*256; int c = el >> 7, q = el & 127;
    sQ[q*40 + c] = Qg[(size_t)c*2304 + qb*128 + q];
  }
  __syncthreads();
  bf16x8 aq[2];
  #pragma unroll
  for (int mt = 0; mt < 2; mt++)
    aq[mt] = *(const bf16x8*)&sQ[(wid*32 + mt*16 + m16)*40 + quad*8];

  float mrun[2][4];
  #pragma unroll
  for (int a = 0; a < 2; a++)
    #pragma unroll
    for (int r = 0; r < 4; r++) mrun[a][r] = -3e38f;

  int cth = tid >> 3, dth = tid & 7;
  // pass A: row maxes
  for (int dt = 0; dt < 25; dt++){
    __syncthreads();
    {
      bf16x8 kv = *(const bf16x8*)&Kg[(size_t)cth*1600 + dt*64 + dth*8];
      #pragma unroll
      for (int j = 0; j < 8; j++) sK[(dth*8 + j)*40 + cth] = (u16)kv[j];
    }
    __syncthreads();
    f32x4 sacc[2][4];
    #pragma unroll
    for (int a = 0; a < 2; a++)
      #pragma unroll
      for (int c = 0; c < 4; c++) sacc[a][c] = (f32x4){0.f,0.f,0.f,0.f};
    #pragma unroll
    for (int nt = 0; nt < 4; nt++){
      bf16x8 bk = *(const bf16x8*)&sK[(nt*16 + m16)*40 + quad*8];
      #pragma unroll
      for (int mt = 0; mt < 2; mt++)
        sacc[mt][nt] = MFMA(aq[mt], bk, sacc[mt][nt]);
    }
    #pragma unroll
    for (int mt = 0; mt < 2; mt++)
      #pragma unroll
      for (int r = 0; r < 4; r++){
        float v = fmaxf(fmaxf(sacc[mt][0][r], sacc[mt][1][r]),
                        fmaxf(sacc[mt][2][r], sacc[mt][3][r]));
        v = fmaxf(v, __shfl_xor(v, 1));
        v = fmaxf(v, __shfl_xor(v, 2));
        v = fmaxf(v, __shfl_xor(v, 4));
        v = fmaxf(v, __shfl_xor(v, 8));
        mrun[mt][r] = fmaxf(mrun[mt][r], v * tauv);
      }
  }
  // pass B
  float lrun[2][4] = {{0.f,0.f,0.f,0.f},{0.f,0.f,0.f,0.f}};
  f32x4 oacc[2][2];
  #pragma unroll
  for (int a = 0; a < 2; a++)
    #pragma unroll
    for (int c = 0; c < 2; c++) oacc[a][c] = (f32x4){0.f,0.f,0.f,0.f};
  u16* myP = sP[wid];
  for (int dt = 0; dt < 25; dt++){
    __syncthreads();
    {
      bf16x8 kv = *(const bf16x8*)&Kg[(size_t)cth*1600 + dt*64 + dth*8];
      #pragma unroll
      for (int j = 0; j < 8; j++) sK[(dth*8 + j)*40 + cth] = (u16)kv[j];
      bf16x8 vv = *(const bf16x8*)&Vg[(size_t)cth*1600 + dt*64 + dth*8];
      *(bf16x8*)&sV[cth*72 + dth*8] = vv;
    }
    __syncthreads();
    f32x4 sacc[2][4];
    #pragma unroll
    for (int a = 0; a < 2; a++)
      #pragma unroll
      for (int c = 0; c < 4; c++) sacc[a][c] = (f32x4){0.f,0.f,0.f,0.f};
    #pragma unroll
    for (int nt = 0; nt < 4; nt++){
      bf16x8 bk = *(const bf16x8*)&sK[(nt*16 + m16)*40 + quad*8];
      #pragma unroll
      for (int mt = 0; mt < 2; mt++)
        sacc[mt][nt] = MFMA(aq[mt], bk, sacc[mt][nt]);
    }
    float ps[2][4] = {{0.f,0.f,0.f,0.f},{0.f,0.f,0.f,0.f}};
    #pragma unroll
    for (int mt = 0; mt < 2; mt++)
      #pragma unroll
      for (int nt = 0; nt < 4; nt++)
        #pragma unroll
        for (int r = 0; r < 4; r++){
          float p = __expf(sacc[mt][nt][r]*tauv - mrun[mt][r]);
          ps[mt][r] += p;
          myP[(mt*16 + quad*4 + r)*72 + nt*16 + m16] = f2b(p);
        }
    #pragma unroll
    for (int mt = 0; mt < 2; mt++)
      #pragma unroll
      for (int r = 0; r < 4; r++){
        float v = ps[mt][r];
        v += __shfl_xor(v, 1);
        v += __shfl_xor(v, 2);
        v += __shfl_xor(v, 4);
        v += __shfl_xor(v, 8);
        lrun[mt][r] += v;
      }
    __syncthreads();   // P visibility (wave-local but keep it simple/safe)
    #pragma unroll
    for (int ks = 0; ks < 2; ks++){
      bf16x8 av[2], bp[2];
      #pragma unroll
      for (int mtc = 0; mtc < 2; mtc++)
        av[mtc] = *(const bf16x8*)&sV[(mtc*16 + m16)*72 + ks*32 + quad*8];
      #pragma unroll
      for (int ntq = 0; ntq < 2; ntq++)
        bp[ntq] = *(const bf16x8*)&myP[(ntq*16 + m16)*72 + ks*32 + quad*8];
      #pragma unroll
      for (int mtc = 0; mtc < 2; mtc++)
        #pragma unroll
        for (int ntq = 0; ntq < 2; ntq++)
          oacc[mtc][ntq] = MFMA(av[mtc], bp[ntq], oacc[mtc][ntq]);
    }
  }
  // l transpose + epilogue (O^T: row=c, col=q)
  if (m16 == 0){
    #pragma unroll
    for (int mt = 0; mt < 2; mt++)
      #pragma unroll
      for (int r = 0; r < 4; r++)
        sL[wid*32 + mt*16 + quad*4 + r] = lrun[mt][r];
  }
  __syncthreads();
  #pragma unroll
  for (int mtc = 0; mtc < 2; mtc++)
    #pragma unroll
    for (int ntq = 0; ntq < 2; ntq++){
      float linv = 1.0f / sL[wid*32 + ntq*16 + m16];
      int q = qb*128 + wid*32 + ntq*16 + m16;
      #pragma unroll
      for (int r = 0; r < 4; r++){
        int c = mtc*16 + quad*4 + r;
        Ab[(ng*32 + c)*2304 + q] = oacc[mtc][ntq][r] * linv;
      }
    }
}

// ---------------- gates + LSTM pointwise ----------------
// grid 576 = n x g x qb(18 x 128 q); 256 thr: (oc = t>>3, q8 = t&7)
__global__ __launch_bounds__(256) void k_final(const float* Ab, const float* Gp,
    const void* Wai, const void* Waf, const void* Wag, const void* Wao,
    const void* bi, const void* bff, const void* bg, const void* bo,
    const void* cprev, void* out, const int* flag){
  int b = blockIdx.x; int qb = b % 18; int g = (b / 18) & 7; int n = b / 144;
  int tid = threadIdx.x; int isbf = *flag;
  __shared__ float sa[32][129];
  __shared__ float sw[4][32][33];
  __shared__ float sbias[4][32];
  size_t ng = (size_t)(n*8 + g);
  for (int i = 0; i < 16; i++){
    int el = tid + i*256; int c = el >> 7, q = el & 127;
    sa[c][q] = Ab[(ng*32 + c)*2304 + qb*128 + q];
  }
  const void* Ws[4] = {Wai, Waf, Wag, Wao};
  #pragma unroll
  for (int k = 0; k < 4; k++)
    for (int i = tid; i < 1024; i += 256){
      int oc = i >> 5, ci = i & 31;
      sw[k][oc][ci] = ldin(Ws[k], (long long)(g*32 + oc)*32 + ci, isbf);
    }
  if (tid < 128){
    int k = tid >> 5, oc = tid & 31;
    const void* Bs[4] = {bi, bff, bg, bo};
    sbias[k][oc] = ldin(Bs[k], g*32 + oc, isbf);
  }
  __syncthreads();
  int oc = tid >> 3, q8 = tid & 7;
  for (int it = 0; it < 16; it++){
    int q = it*8 + q8;
    int qg = qb*128 + q;
    float a0 = sbias[0][oc], a1 = sbias[1][oc], a2 = sbias[2][oc], a3 = sbias[3][oc];
    #pragma unroll
    for (int ci = 0; ci < 32; ci++){
      float av = sa[ci][q];
      a0 += sw[0][oc][ci]*av;
      a1 += sw[1][oc][ci]*av;
      a2 += sw[2][oc][ci]*av;
      a3 += sw[3][oc][ci]*av;
    }
    a0 += Gp[((ng*4 + 0)*32 + oc)*2304 + qg];
    a1 += Gp[((ng*4 + 1)*32 + oc)*2304 + qg];
    a2 += Gp[((ng*4 + 2)*32 + oc)*2304 + qg];
    a3 += Gp[((ng*4 + 3)*32 + oc)*2304 + qg];
    float gi = sigm(a0), gf = sigm(a1), gv = tanh_f(a2), go = sigm(a3);
    long long cidx = ((long long)n*256 + g*32 + oc)*2304 + qg;
    float cp = ldin(cprev, cidx, isbf);
    float cn = gf*cp + gi*gv;
    float hv = go * tanh_f(cn);
    if (isbf) ((u16*)out)[cidx] = f2b(hv);
    else      ((float*)out)[cidx] = hv;
  }
}

extern "C" void kernel_launch(void* const* d_in, const int* in_sizes, int n_in,
                              void* d_out, int out_size, void* d_ws, size_t ws_size,
                              hipStream_t stream){
  const void* inp  = d_in[0];
  const void* h    = d_in[1];
  const void* cpv  = d_in[2];
  const void* Wx   = d_in[3];
  const void* Wxg  = d_in[4];
  const void* tau  = d_in[5];
  const void* Wq   = d_in[6];
  const void* Wk   = d_in[7];
  const void* Wv   = d_in[8];
  const void* Wai  = d_in[9];  const void* Wxi = d_in[10]; const void* bi = d_in[11];
  const void* Waf  = d_in[12]; const void* Wxf = d_in[13]; const void* bff = d_in[14];
  const void* Wag  = d_in[15]; const void* Wxg2 = d_in[16]; const void* bg = d_in[17];
  const void* Wao  = d_in[18]; const void* Wxo = d_in[19]; const void* bo = d_in[20];

  char* ws = (char*)d_ws;
  int*  flag = (int*)(ws + OFF_FLAG);
  u16*  WB = (u16*)(ws + OFF_WB);
  u16*  Wp = (u16*)(ws + OFF_WP);
  u16*  UT = (u16*)(ws + OFF_UT);
  u16*  XH = (u16*)(ws + OFF_XH);
  u16*  Qb = (u16*)(ws + OFF_QB);
  u16*  Kb = (u16*)(ws + OFF_KB);
  u16*  Vb = (u16*)(ws + OFF_VB);
  float* Gp = (float*)(ws + OFF_GP);
  float* Ab = (float*)(ws + OFF_AB);

  hipMemsetAsync(XH, 0, SZ_XH, stream);                 // zero-padded conv input
  k_probe<<<1, 256, 0, stream>>>((const unsigned*)inp, flag);
  k_packw<<<1792, 256, 0, stream>>>(Wq, Wk, Wv, Wxi, Wxf, Wxg2, Wxo, WB, flag);
  k_packp<<<320, 256, 0, stream>>>(Wx, Wxg, Wp, flag);
  k_ut<<<360, 256, 0, stream>>>(inp, h, UT, XH, flag);
  k_proj<<<64, 384, 0, stream>>>(Wp, UT, XH);
  k_conv<<<512, 384, 0, stream>>>(WB, XH, Qb, Kb, Vb, Gp);
  k_attn<<<576, 256, 0, stream>>>(Qb, Kb, Vb, Ab, tau, flag);
  k_final<<<576, 256, 0, stream>>>(Ab, Gp, Wai, Waf, Wag, Wao,
                                   bi, bff, bg, bo, cpv, d_out, flag);
}

// Round 3
// 486.023 us; speedup vs baseline: 1.2125x; 1.2125x over previous
//
#include <hip/hip_runtime.h>
#include <stdint.h>

typedef unsigned short u16;
typedef float f32x4 __attribute__((ext_vector_type(4)));
typedef short bf16x8 __attribute__((ext_vector_type(8)));

#define MFMA(a,b,c) __builtin_amdgcn_mfma_f32_16x16x32_bf16((a),(b),(c),0,0,0)

__device__ __forceinline__ u16 f2b(float f){
  union { float f; unsigned u; } x; x.f = f;
  unsigned r = x.u + 0x7FFFu + ((x.u >> 16) & 1u);   // RNE
  return (u16)(r >> 16);
}
__device__ __forceinline__ float b2f(u16 b){
  union { unsigned u; float f; } x; x.u = ((unsigned)b) << 16;
  return x.f;
}
// runtime-dtype input load (flag: 1=bf16 inputs, 0=fp32 inputs)
__device__ __forceinline__ float ldin(const void* p, long long i, int isbf){
  return isbf ? b2f(((const u16*)p)[i]) : ((const float*)p)[i];
}
typedef const __attribute__((address_space(1))) void gas_t;
typedef __attribute__((address_space(3))) void sas_t;
__device__ __forceinline__ void gl16(const void* g, void* l){
  __builtin_amdgcn_global_load_lds((gas_t*)g, (sas_t*)l, 16, 0, 0);
}
__device__ __forceinline__ float sigm(float x){ return 1.f/(1.f + __expf(-x)); }
__device__ __forceinline__ float tanh_f(float x){
  float e2 = __expf(-2.f*fabsf(x));
  float t = (1.f - e2)/(1.f + e2);
  return copysignf(t, x);
}

// N=4 I=64 C=256 G=8 Cg=32 K=9 H=W=48 HW=2304 Hd=Wd=40 D=1600 pad=4 (56x56 padded)
static constexpr size_t OFF_FLAG = 0;
static constexpr size_t OFF_WB = 256;                     // conv w bf16 [g][81][224][64], ci-chunks xor oc&7
static constexpr size_t SZ_WB  = (size_t)8*81*224*64*2;
static constexpr size_t OFF_WP = OFF_WB + SZ_WB;          // proj w bf16 [256][320], chunk xor oc&7
static constexpr size_t SZ_WP  = (size_t)256*320*2;
static constexpr size_t OFF_UT = OFF_WP + SZ_WP;          // [n][2304][320] bf16 (inp;h transposed)
static constexpr size_t SZ_UT  = (size_t)4*2304*320*2;
static constexpr size_t OFF_XH = OFF_UT + SZ_UT;          // [n][g][56][56][64] bf16, zero pad
static constexpr size_t SZ_XH  = (size_t)32*3136*64*2;
static constexpr size_t OFF_QB = OFF_XH + SZ_XH;          // [n][g][32][2304] bf16
static constexpr size_t SZ_QB  = (size_t)32*32*2304*2;
static constexpr size_t OFF_KB = OFF_QB + SZ_QB;          // [n][g][32][1600] bf16
static constexpr size_t SZ_KB  = (size_t)32*32*1600*2;
static constexpr size_t OFF_VB = OFF_KB + SZ_KB;          // [n][g][32][1600] bf16
static constexpr size_t OFF_GP = OFF_VB + SZ_KB;          // [n][g][4][32][2304] f32 gate pre-acts
static constexpr size_t SZ_GP  = (size_t)32*4*32*2304*4;
static constexpr size_t OFF_AB = OFF_GP + SZ_GP;          // [n][g][32][2304] f32 attention out
static constexpr size_t SZ_AB  = (size_t)32*32*2304*4;

// ---------------- probe: detect bf16 vs fp32 inputs ----------------
__global__ void k_probe(const unsigned* u, int* flag){
  int t = threadIdx.x;
  unsigned v = u[t];
  unsigned e = (v >> 7) & 0xFF;     // exponent field of low-16 as bf16
  int is = (e >= 0x70 && e <= 0x88) ? 1 : 0;
  unsigned long long m = __ballot(is);
  __shared__ int cnt[4];
  if ((t & 63) == 0) cnt[t >> 6] = __popcll(m);
  __syncthreads();
  if (t == 0) *flag = (cnt[0]+cnt[1]+cnt[2]+cnt[3] >= 128) ? 1 : 0;
}

// ---------------- pack conv weights ----------------
// grid 1792 = g(8) x conv(7) x ocl(32); WB[g][kk][oc=conv*32+ocl][swz(ci)]
__global__ void k_packw(const void* Wq, const void* Wk, const void* Wv,
                        const void* Wi, const void* Wf, const void* Wg,
                        const void* Wo, u16* WB, const int* flag){
  int b = blockIdx.x; int ocl = b & 31; int tt = (b >> 5) % 7; int g = b / 224;
  int tid = threadIdx.x; int isbf = *flag;
  const void* srcs[7] = {Wq, Wk, Wv, Wi, Wf, Wg, Wo};
  const void* src = srcs[tt];
  __shared__ float s[5184];
  long long base = (long long)(g*32 + ocl) * 5184;   // [oc][ci=64][9][9]
  for (int i = tid; i < 5184; i += 256) s[i] = ldin(src, base + i, isbf);
  __syncthreads();
  int oc = tt*32 + ocl;
  for (int i = tid; i < 5184; i += 256){
    int kk = i >> 6, ci = i & 63;
    int pos = ((((ci >> 3) ^ (ocl & 7)) << 3) | (ci & 7));
    WB[((size_t)(g*81 + kk)*224 + oc)*64 + pos] = f2b(s[ci*81 + kk]);
  }
}

// ---------------- pack proj weights [256][320] = [Wx|Wxg], chunk-swizzled ----------------
__global__ void k_packp(const void* Wx, const void* Wxg, u16* Wp, const int* flag){
  int el = blockIdx.x*256 + threadIdx.x;   // 81920
  int isbf = *flag;
  if (el >= 81920) return;
  int oc = el / 320, k = el % 320;
  float v = (k < 64) ? ldin(Wx, (long long)oc*64 + k, isbf)
                     : ldin(Wxg, (long long)oc*256 + (k - 64), isbf);
  int win = k >> 6, pos = k & 63;
  int dpos = (win << 6) | ((((pos >> 3) ^ (oc & 7)) << 3)) | (pos & 7);
  Wp[(size_t)oc*320 + dpos] = f2b(v);
}

// ---------------- build U_T [n][q][320] + fill h-part of xh_pad ----------------
// grid 360 = n(4) x s(5: inp, h0..h3) x qb(18)
__global__ void k_ut(const void* inp, const void* h, u16* UT, u16* xh, const int* flag){
  int b = blockIdx.x; int qb = b % 18; int s = (b / 18) % 5; int n = b / 90;
  int tid = threadIdx.x; int isbf = *flag;
  __shared__ float sb[64][129];
  const void* src = (s == 0) ? inp : h;
  long long base = (s == 0) ? (long long)n*64*2304 : ((long long)n*256 + (s-1)*64)*2304;
  for (int i = 0; i < 32; i++){
    int el = tid + i*256; int r = el >> 7, q = el & 127;
    sb[r][q] = ldin(src, base + (long long)r*2304 + qb*128 + q, isbf);
  }
  __syncthreads();
  int koff = (s == 0) ? 0 : 64 + (s-1)*64;
  for (int i = 0; i < 4; i++){
    int chunk = tid + i*256;                 // 1024 chunks of 8
    int q = chunk >> 3, c8 = chunk & 7;
    bf16x8 v;
    #pragma unroll
    for (int j = 0; j < 8; j++) v[j] = (short)f2b(sb[c8*8 + j][q]);
    *(bf16x8*)&UT[((size_t)(n*2304 + qb*128 + q))*320 + koff + c8*8] = v;
  }
  if (s > 0){
    for (int i = 0; i < 4; i++){
      int chunk = tid + i*256;               // q(128) x gg(2) x seg(4)
      int q = chunk >> 3, gg = (chunk >> 2) & 1, seg = chunk & 3;
      int g = (s-1)*2 + gg;
      int qg = qb*128 + q; int y = qg / 48, x = qg - y*48;
      bf16x8 v;
      #pragma unroll
      for (int j = 0; j < 8; j++) v[j] = (short)f2b(sb[gg*32 + seg*8 + j][q]);
      *(bf16x8*)&xh[(((size_t)((n*8+g)*56 + y+4))*56 + (x+4))*64 + 32 + seg*8] = v;
    }
  }
}

// ---------------- proj GEMM: x = [Wx|Wxg]·[inp;h] -> xh_pad ci[0:32) ----------------
__global__ __launch_bounds__(384) void k_proj(const u16* Wp, const u16* UT, u16* xh){
  int b = blockIdx.x; int qblk = b & 15; int n = b >> 4;
  int tid = threadIdx.x; int lane = tid & 63; int wid = tid >> 6;
  int wm = wid % 3, wn = wid / 3;
  int quad = lane >> 4, m16 = lane & 15;
  __shared__ __align__(16) u16 lA[144*64];
  __shared__ __align__(16) u16 lB[256*64];
  size_t abase[3];
  #pragma unroll
  for (int r = 0; r < 3; r++){
    int chunk = tid + r*384; int j = chunk >> 3, cs = chunk & 7;
    int cc = cs ^ (j & 7);
    abase[r] = ((size_t)(n*2304 + qblk*144 + j))*320 + cc*8;
  }
  f32x4 acc[3][8];
  #pragma unroll
  for (int a = 0; a < 3; a++)
    #pragma unroll
    for (int c = 0; c < 8; c++) acc[a][c] = (f32x4){0.f,0.f,0.f,0.f};

  for (int kb = 0; kb < 5; kb++){
    __syncthreads();
    #pragma unroll
    for (int r = 0; r < 3; r++)
      gl16(&UT[abase[r] + kb*64], &lA[(tid + r*384)*8]);
    #pragma unroll
    for (int r = 0; r < 6; r++){
      int chunk = tid + r*384;
      if (chunk < 2048)
        gl16(&Wp[(size_t)(chunk >> 3)*320 + kb*64 + (chunk & 7)*8], &lB[chunk*8]);
    }
    __syncthreads();
    #pragma unroll
    for (int ks = 0; ks < 2; ks++){
      int sw = ((ks*4 + quad) ^ (lane & 7))*8;
      bf16x8 af[3], bfr[8];
      #pragma unroll
      for (int mt = 0; mt < 3; mt++)
        af[mt] = *(const bf16x8*)&lA[(wm*48 + mt*16 + m16)*64 + sw];
      #pragma unroll
      for (int nt = 0; nt < 8; nt++)
        bfr[nt] = *(const bf16x8*)&lB[(wn*128 + nt*16 + m16)*64 + sw];
      #pragma unroll
      for (int mt = 0; mt < 3; mt++)
        #pragma unroll
        for (int nt = 0; nt < 8; nt++)
          acc[mt][nt] = MFMA(af[mt], bfr[nt], acc[mt][nt]);
    }
  }
  #pragma unroll
  for (int mt = 0; mt < 3; mt++)
    #pragma unroll
    for (int nt = 0; nt < 8; nt++)
      #pragma unroll
      for (int r = 0; r < 4; r++){
        int q = qblk*144 + wm*48 + mt*16 + quad*4 + r;
        int oc = wn*128 + nt*16 + m16;
        int y = q / 48, x = q - y*48;
        int g = oc >> 5, ci = oc & 31;
        xh[(((size_t)((n*8+g)*56 + y+4))*56 + (x+4))*64 + ci] = f2b(acc[mt][nt][r]);
      }
}

// ---------------- fused 7-conv implicit GEMM, pipelined ----------------
// grid 256 = n(4) x g(8) x qb(8); block 768 thr = 12 waves (wm 2 x 112oc, wn 6 x 48sp)
// tile 224 oc x 288 sp (6 rows). LDS: A dbuf 2x28KB + B dbuf 2x36KB = 128KB dynamic.
// Single barrier per tap; prefetch tap kk+1 while computing kk.
__global__ __launch_bounds__(768) void k_conv(const u16* WB, const u16* xh,
                                              u16* Qb, u16* Kb, u16* Vb, float* Gp){
  extern __shared__ __align__(16) u16 sm[];
  int b = blockIdx.x; int qb = b & 7; int gg = (b >> 3) & 7; int n = b >> 6;
  int tid = threadIdx.x; int lane = tid & 63; int wid = tid >> 6;
  int wm = wid & 1, wn = wid >> 1;        // wm 0..1, wn 0..5
  int quad = lane >> 4, m16 = lane & 15;
  int y0 = qb*6;
  const u16* WBg = WB + (size_t)gg*81*14336;
  const u16* xg  = xh + (size_t)((n*8+gg)*3136)*64;
  // B chunk descriptors: 2304 chunks = 3/thread
  int bsrc[3], bdst[3];
  #pragma unroll
  for (int r = 0; r < 3; r++){
    int c = tid + r*768;
    int dy = c / 384, rem = c % 384;
    int col = rem >> 3, cs = rem & 7;
    int sc = cs ^ (col & 7);
    bsrc[r] = ((y0+dy)*56 + col)*64 + sc*8;
    bdst[r] = c*8;
  }
  f32x4 acc[7][3];
  #pragma unroll
  for (int a = 0; a < 7; a++)
    #pragma unroll
    for (int c = 0; c < 3; c++) acc[a][c] = (f32x4){0.f,0.f,0.f,0.f};

  // prologue: stage tap 0 into buffer 0  (A at sm, B at sm+28672; dbuf strides 14336/18432)
  {
    u16* A0 = sm;
    u16* B0 = sm + 28672;
    gl16(&WBg[tid*8],       &A0[tid*8]);
    gl16(&WBg[(tid+768)*8], &A0[(tid+768)*8]);
    if (tid < 256) gl16(&WBg[(tid+1536)*8], &A0[(tid+1536)*8]);
    #pragma unroll
    for (int r = 0; r < 3; r++)
      gl16(&xg[bsrc[r]], &B0[bdst[r]]);
  }

  int ky = 0, kx = 0;
  for (int kk = 0; kk < 81; kk++){
    __syncthreads();     // drains vmcnt: buf[kk&1] ready; all waves done with buf[(kk-1)&1]
    if (kk < 80){
      int kx1 = kx + 1, ky1 = ky;
      if (kx1 == 9){ kx1 = 0; ky1++; }
      int nb = (kk+1) & 1;
      u16* An = sm + nb*14336;
      u16* Bn = sm + 28672 + nb*18432;
      const u16* As = WBg + (size_t)(kk+1)*14336;
      gl16(&As[tid*8],       &An[tid*8]);
      gl16(&As[(tid+768)*8], &An[(tid+768)*8]);
      if (tid < 256) gl16(&As[(tid+1536)*8], &An[(tid+1536)*8]);
      int koff = (ky1*56 + kx1)*64;
      #pragma unroll
      for (int r = 0; r < 3; r++)
        gl16(&xg[bsrc[r] + koff], &Bn[bdst[r]]);
    }
    const u16* A = sm + (kk&1)*14336;
    const u16* B = sm + 28672 + (kk&1)*18432;
    #pragma unroll
    for (int ks = 0; ks < 2; ks++){
      bf16x8 af[7], bfr[3];
      #pragma unroll
      for (int mt = 0; mt < 7; mt++){
        int rr = wm*112 + mt*16 + m16;
        af[mt] = *(const bf16x8*)&A[rr*64 + (((ks*4+quad) ^ (rr&7))*8)];
      }
      #pragma unroll
      for (int nt = 0; nt < 3; nt++){
        int sp = wn*48 + nt*16 + m16;
        bfr[nt] = *(const bf16x8*)&B[sp*64 + (((ks*4+quad) ^ (sp&7))*8)];
      }
      #pragma unroll
      for (int mt = 0; mt < 7; mt++)
        #pragma unroll
        for (int nt = 0; nt < 3; nt++)
          acc[mt][nt] = MFMA(af[mt], bfr[nt], acc[mt][nt]);
    }
    kx++; if (kx == 9){ kx = 0; ky++; }
  }
  // epilogue: row = oc, col = spatial
  int y = y0 + wn;
  size_t ng = (size_t)(n*8 + gg);
  #pragma unroll
  for (int mt = 0; mt < 7; mt++){
    int ocb = wm*112 + mt*16 + quad*4;
    #pragma unroll
    for (int nt = 0; nt < 3; nt++){
      int x = nt*16 + m16;
      int q = y*48 + x;
      #pragma unroll
      for (int r = 0; r < 4; r++){
        float v = acc[mt][nt][r];
        int oc = ocb + r;
        int t7 = oc >> 5, ocl = oc & 31;
        if (t7 == 0){
          Qb[(ng*32 + ocl)*2304 + q] = f2b(v);
        } else if (t7 <= 2){
          if ((unsigned)(y-4) < 40u && (unsigned)(x-4) < 40u){
            int d = (y-4)*40 + (x-4);
            (t7 == 1 ? Kb : Vb)[(ng*32 + ocl)*1600 + d] = f2b(v);
          }
        } else {
          Gp[((ng*4 + (t7-3))*32 + ocl)*2304 + q] = v;
        }
      }
    }
  }
}

// ---------------- attention: S=tau Q^T K, softmax over d, O^T = V P^T ----------------
__global__ __launch_bounds__(256) void k_attn(const u16* Qb, const u16* Kb, const u16* Vb,
                                              float* Ab, const void* tau, const int* flag){
  int b = blockIdx.x; int qb = b % 18; int g = (b / 18) & 7; int n = b / 144;
  int tid = threadIdx.x; int lane = tid & 63; int wid = tid >> 6;
  int quad = lane >> 4, m16 = lane & 15;
  int isbf = *flag;
  __shared__ __align__(16) u16 sQ[128*40];     // [q][c] stride 40
  __shared__ __align__(16) u16 sK[64*40];      // [d][c] stride 40
  __shared__ __align__(16) u16 sV[32*72];      // [c][d] stride 72
  __shared__ __align__(16) u16 sP[4][32*72];   // per-wave [q][d] stride 72
  __shared__ float sL[128];
  size_t ng = (size_t)(n*8 + g);
  const u16* Qg = Qb + ng*32*2304;
  const u16* Kg = Kb + ng*32*1600;
  const u16* Vg = Vb + ng*32*1600;
  float tauv = ldin(tau, g, isbf);
  for (int i = 0; i < 16; i++){
    int el = tid + i*256; int c = el >> 7, q = el & 127;
    sQ[q*40 + c] = Qg[(size_t)c*2304 + qb*128 + q];
  }
  __syncthreads();
  bf16x8 aq[2];
  #pragma unroll
  for (int mt = 0; mt < 2; mt++)
    aq[mt] = *(const bf16x8*)&sQ[(wid*32 + mt*16 + m16)*40 + quad*8];

  float mrun[2][4];
  #pragma unroll
  for (int a = 0; a < 2; a++)
    #pragma unroll
    for (int r = 0; r < 4; r++) mrun[a][r] = -3e38f;

  int cth = tid >> 3, dth = tid & 7;
  for (int dt = 0; dt < 25; dt++){
    __syncthreads();
    {
      bf16x8 kv = *(const bf16x8*)&Kg[(size_t)cth*1600 + dt*64 + dth*8];
      #pragma unroll
      for (int j = 0; j < 8; j++) sK[(dth*8 + j)*40 + cth] = (u16)kv[j];
    }
    __syncthreads();
    f32x4 sacc[2][4];
    #pragma unroll
    for (int a = 0; a < 2; a++)
      #pragma unroll
      for (int c = 0; c < 4; c++) sacc[a][c] = (f32x4){0.f,0.f,0.f,0.f};
    #pragma unroll
    for (int nt = 0; nt < 4; nt++){
      bf16x8 bk = *(const bf16x8*)&sK[(nt*16 + m16)*40 + quad*8];
      #pragma unroll
      for (int mt = 0; mt < 2; mt++)
        sacc[mt][nt] = MFMA(aq[mt], bk, sacc[mt][nt]);
    }
    #pragma unroll
    for (int mt = 0; mt < 2; mt++)
      #pragma unroll
      for (int r = 0; r < 4; r++){
        float v = fmaxf(fmaxf(sacc[mt][0][r], sacc[mt][1][r]),
                        fmaxf(sacc[mt][2][r], sacc[mt][3][r]));
        v = fmaxf(v, __shfl_xor(v, 1));
        v = fmaxf(v, __shfl_xor(v, 2));
        v = fmaxf(v, __shfl_xor(v, 4));
        v = fmaxf(v, __shfl_xor(v, 8));
        mrun[mt][r] = fmaxf(mrun[mt][r], v * tauv);
      }
  }
  float lrun[2][4] = {{0.f,0.f,0.f,0.f},{0.f,0.f,0.f,0.f}};
  f32x4 oacc[2][2];
  #pragma unroll
  for (int a = 0; a < 2; a++)
    #pragma unroll
    for (int c = 0; c < 2; c++) oacc[a][c] = (f32x4){0.f,0.f,0.f,0.f};
  u16* myP = sP[wid];
  for (int dt = 0; dt < 25; dt++){
    __syncthreads();
    {
      bf16x8 kv = *(const bf16x8*)&Kg[(size_t)cth*1600 + dt*64 + dth*8];
      #pragma unroll
      for (int j = 0; j < 8; j++) sK[(dth*8 + j)*40 + cth] = (u16)kv[j];
      bf16x8 vv = *(const bf16x8*)&Vg[(size_t)cth*1600 + dt*64 + dth*8];
      *(bf16x8*)&sV[cth*72 + dth*8] = vv;
    }
    __syncthreads();
    f32x4 sacc[2][4];
    #pragma unroll
    for (int a = 0; a < 2; a++)
      #pragma unroll
      for (int c = 0; c < 4; c++) sacc[a][c] = (f32x4){0.f,0.f,0.f,0.f};
    #pragma unroll
    for (int nt = 0; nt < 4; nt++){
      bf16x8 bk = *(const bf16x8*)&sK[(nt*16 + m16)*40 + quad*8];
      #pragma unroll
      for (int mt = 0; mt < 2; mt++)
        sacc[mt][nt] = MFMA(aq[mt], bk, sacc[mt][nt]);
    }
    float ps[2][4] = {{0.f,0.f,0.f,0.f},{0.f,0.f,0.f,0.f}};
    #pragma unroll
    for (int mt = 0; mt < 2; mt++)
      #pragma unroll
      for (int nt = 0; nt < 4; nt++)
        #pragma unroll
        for (int r = 0; r < 4; r++){
          float p = __expf(sacc[mt][nt][r]*tauv - mrun[mt][r]);
          ps[mt][r] += p;
          myP[(mt*16 + quad*4 + r)*72 + nt*16 + m16] = f2b(p);
        }
    #pragma unroll
    for (int mt = 0; mt < 2; mt++)
      #pragma unroll
      for (int r = 0; r < 4; r++){
        float v = ps[mt][r];
        v += __shfl_xor(v, 1);
        v += __shfl_xor(v, 2);
        v += __shfl_xor(v, 4);
        v += __shfl_xor(v, 8);
        lrun[mt][r] += v;
      }
    __syncthreads();
    #pragma unroll
    for (int ks = 0; ks < 2; ks++){
      bf16x8 av[2], bp[2];
      #pragma unroll
      for (int mtc = 0; mtc < 2; mtc++)
        av[mtc] = *(const bf16x8*)&sV[(mtc*16 + m16)*72 + ks*32 + quad*8];
      #pragma unroll
      for (int ntq = 0; ntq < 2; ntq++)
        bp[ntq] = *(const bf16x8*)&myP[(ntq*16 + m16)*72 + ks*32 + quad*8];
      #pragma unroll
      for (int mtc = 0; mtc < 2; mtc++)
        #pragma unroll
        for (int ntq = 0; ntq < 2; ntq++)
          oacc[mtc][ntq] = MFMA(av[mtc], bp[ntq], oacc[mtc][ntq]);
    }
  }
  if (m16 == 0){
    #pragma unroll
    for (int mt = 0; mt < 2; mt++)
      #pragma unroll
      for (int r = 0; r < 4; r++)
        sL[wid*32 + mt*16 + quad*4 + r] = lrun[mt][r];
  }
  __syncthreads();
  #pragma unroll
  for (int mtc = 0; mtc < 2; mtc++)
    #pragma unroll
    for (int ntq = 0; ntq < 2; ntq++){
      float linv = 1.0f / sL[wid*32 + ntq*16 + m16];
      int q = qb*128 + wid*32 + ntq*16 + m16;
      #pragma unroll
      for (int r = 0; r < 4; r++){
        int c = mtc*16 + quad*4 + r;
        Ab[(ng*32 + c)*2304 + q] = oacc[mtc][ntq][r] * linv;
      }
    }
}

// ---------------- gates + LSTM pointwise ----------------
__global__ __launch_bounds__(256) void k_final(const float* Ab, const float* Gp,
    const void* Wai, const void* Waf, const void* Wag, const void* Wao,
    const void* bi, const void* bff, const void* bg, const void* bo,
    const void* cprev, void* out, const int* flag){
  int b = blockIdx.x; int qb = b % 18; int g = (b / 18) & 7; int n = b / 144;
  int tid = threadIdx.x; int isbf = *flag;
  __shared__ float sa[32][129];
  __shared__ float sw[4][32][33];
  __shared__ float sbias[4][32];
  size_t ng = (size_t)(n*8 + g);
  for (int i = 0; i < 16; i++){
    int el = tid + i*256; int c = el >> 7, q = el & 127;
    sa[c][q] = Ab[(ng*32 + c)*2304 + qb*128 + q];
  }
  const void* Ws[4] = {Wai, Waf, Wag, Wao};
  #pragma unroll
  for (int k = 0; k < 4; k++)
    for (int i = tid; i < 1024; i += 256){
      int oc = i >> 5, ci = i & 31;
      sw[k][oc][ci] = ldin(Ws[k], (long long)(g*32 + oc)*32 + ci, isbf);
    }
  if (tid < 128){
    int k = tid >> 5, oc = tid & 31;
    const void* Bs[4] = {bi, bff, bg, bo};
    sbias[k][oc] = ldin(Bs[k], g*32 + oc, isbf);
  }
  __syncthreads();
  int oc = tid >> 3, q8 = tid & 7;
  for (int it = 0; it < 16; it++){
    int q = it*8 + q8;
    int qg = qb*128 + q;
    float a0 = sbias[0][oc], a1 = sbias[1][oc], a2 = sbias[2][oc], a3 = sbias[3][oc];
    #pragma unroll
    for (int ci = 0; ci < 32; ci++){
      float av = sa[ci][q];
      a0 += sw[0][oc][ci]*av;
      a1 += sw[1][oc][ci]*av;
      a2 += sw[2][oc][ci]*av;
      a3 += sw[3][oc][ci]*av;
    }
    a0 += Gp[((ng*4 + 0)*32 + oc)*2304 + qg];
    a1 += Gp[((ng*4 + 1)*32 + oc)*2304 + qg];
    a2 += Gp[((ng*4 + 2)*32 + oc)*2304 + qg];
    a3 += Gp[((ng*4 + 3)*32 + oc)*2304 + qg];
    float gi = sigm(a0), gf = sigm(a1), gv = tanh_f(a2), go = sigm(a3);
    long long cidx = ((long long)n*256 + g*32 + oc)*2304 + qg;
    float cp = ldin(cprev, cidx, isbf);
    float cn = gf*cp + gi*gv;
    float hv = go * tanh_f(cn);
    if (isbf) ((u16*)out)[cidx] = f2b(hv);
    else      ((float*)out)[cidx] = hv;
  }
}

extern "C" void kernel_launch(void* const* d_in, const int* in_sizes, int n_in,
                              void* d_out, int out_size, void* d_ws, size_t ws_size,
                              hipStream_t stream){
  const void* inp  = d_in[0];
  const void* h    = d_in[1];
  const void* cpv  = d_in[2];
  const void* Wx   = d_in[3];
  const void* Wxg  = d_in[4];
  const void* tau  = d_in[5];
  const void* Wq   = d_in[6];
  const void* Wk   = d_in[7];
  const void* Wv   = d_in[8];
  const void* Wai  = d_in[9];  const void* Wxi = d_in[10]; const void* bi = d_in[11];
  const void* Waf  = d_in[12]; const void* Wxf = d_in[13]; const void* bff = d_in[14];
  const void* Wag  = d_in[15]; const void* Wxg2 = d_in[16]; const void* bg = d_in[17];
  const void* Wao  = d_in[18]; const void* Wxo = d_in[19]; const void* bo = d_in[20];

  char* ws = (char*)d_ws;
  int*  flag = (int*)(ws + OFF_FLAG);
  u16*  WB = (u16*)(ws + OFF_WB);
  u16*  Wp = (u16*)(ws + OFF_WP);
  u16*  UT = (u16*)(ws + OFF_UT);
  u16*  XH = (u16*)(ws + OFF_XH);
  u16*  Qb = (u16*)(ws + OFF_QB);
  u16*  Kb = (u16*)(ws + OFF_KB);
  u16*  Vb = (u16*)(ws + OFF_VB);
  float* Gp = (float*)(ws + OFF_GP);
  float* Ab = (float*)(ws + OFF_AB);

  (void)hipFuncSetAttribute(reinterpret_cast<const void*>(k_conv),
                            hipFuncAttributeMaxDynamicSharedMemorySize, 131072);

  (void)hipMemsetAsync(XH, 0, SZ_XH, stream);
  k_probe<<<1, 256, 0, stream>>>((const unsigned*)inp, flag);
  k_packw<<<1792, 256, 0, stream>>>(Wq, Wk, Wv, Wxi, Wxf, Wxg2, Wxo, WB, flag);
  k_packp<<<320, 256, 0, stream>>>(Wx, Wxg, Wp, flag);
  k_ut<<<360, 256, 0, stream>>>(inp, h, UT, XH, flag);
  k_proj<<<64, 384, 0, stream>>>(Wp, UT, XH);
  k_conv<<<256, 768, 131072, stream>>>(WB, XH, Qb, Kb, Vb, Gp);
  k_attn<<<576, 256, 0, stream>>>(Qb, Kb, Vb, Ab, tau, flag);
  k_final<<<576, 256, 0, stream>>>(Ab, Gp, Wai, Waf, Wag, Wao,
                                   bi, bff, bg, bo, cpv, d_out, flag);
}